// Round 8
// baseline (133.109 us; speedup 1.0000x reference)
//
#include <hip/hip_runtime.h>
#include <math.h>

#define N_INW     1024
#define N_DEPTH   8
#define N_GROW    512
#define N_BATCH   4096
#define N_THREADS 128    // 2 independent waves; wave cp owns cols {2cp,2cp+1}
#define N_LAYERS  64

typedef __attribute__((ext_vector_type(2))) float F2;

// cs table planes: layer g: cos plane at [(2g)*512 + p], sin plane at [(2g+1)*512 + p]
__global__ void precompute_cs_kernel(const float* __restrict__ angles,
                                     float* __restrict__ cs) {
    int i = blockIdx.x * blockDim.x + threadIdx.x;
    if (i < N_LAYERS * 512) {
        int g = i >> 9, p = i & 511;
        float a = angles[i];
        cs[(2 * g) * 512 + p]     = cosf(a);
        cs[(2 * g + 1) * 512 + p] = sinf(a);
    }
}

// LDS layout: 4 cols/row as 2 F2 slots; 2 pad elems per 16 rows (keeps 8B align).
// elem(r, cp) = 4r + 2*(r>>4) + 2cp  ->  byte = 16r + 8*(r>>4) + 8cp.
// Total: 288 groups * 66 elems * 4B = 76032 B -> 2 WGs/CU.
#define ADDR(r) (((r) << 4) + (((r) >> 4) << 3) + cpo)

#define LD2(A)    (*(const F2*)(L + (A)))
#define ST2(A, V) do { *(F2*)(L + (A)) = (V); } while (0)

// load cos/sin for table layer g into four named float4s (c[0..7], s[0..7])
#define LDCS(g, CA, CB, SA, SB) do { if (USE_TABLE) {                          \
    const float4* _c = (const float4*)(cs_tab + (2*(g))*512 + (blk<<3));       \
    const float4* _s = (const float4*)(cs_tab + (2*(g)+1)*512 + (blk<<3));     \
    CA = _c[0]; CB = _c[1]; SA = _s[0]; SB = _s[1];                            \
  } else {                                                                     \
    const float4* _p = (const float4*)(angles + (g)*512 + (blk<<3));           \
    float4 _a = _p[0], _b = _p[1];                                             \
    __sincosf(_a.x, &SA.x, &CA.x); __sincosf(_a.y, &SA.y, &CA.y);              \
    __sincosf(_a.z, &SA.z, &CA.z); __sincosf(_a.w, &SA.w, &CA.w);              \
    __sincosf(_b.x, &SB.x, &CB.x); __sincosf(_b.y, &SB.y, &CB.y);              \
    __sincosf(_b.z, &SB.z, &CB.z); __sincosf(_b.w, &SB.w, &CB.w);              \
  } } while (0)

// packed 2-col rotation of one (lo,hi) pair by scalar (c,s) -> v_pk_* ops
#define ROTP(LO, HI, CC, SS) do { F2 _l = LO, _h = HI;                         \
    LO = CC * _l + SS * _h; HI = CC * _h - SS * _l; } while (0)

// stride-1: pairs (2k,2k+1), la=k
#define ROTS1(CA,CB,SA,SB) do {                                                \
    ROTP(x0,x1,CA.x,SA.x);  ROTP(x2,x3,CA.y,SA.y);                             \
    ROTP(x4,x5,CA.z,SA.z);  ROTP(x6,x7,CA.w,SA.w);                             \
    ROTP(x8,x9,CB.x,SB.x);  ROTP(x10,x11,CB.y,SB.y);                           \
    ROTP(x12,x13,CB.z,SB.z);ROTP(x14,x15,CB.w,SB.w); } while (0)
// stride-2: pairs (j,j+2), j in {0,1,4,5,8,9,12,13}, la=(j/4)*2+j%2
#define ROTS2(CA,CB,SA,SB) do {                                                \
    ROTP(x0,x2,CA.x,SA.x);  ROTP(x1,x3,CA.y,SA.y);                             \
    ROTP(x4,x6,CA.z,SA.z);  ROTP(x5,x7,CA.w,SA.w);                             \
    ROTP(x8,x10,CB.x,SB.x); ROTP(x9,x11,CB.y,SB.y);                            \
    ROTP(x12,x14,CB.z,SB.z);ROTP(x13,x15,CB.w,SB.w); } while (0)
// stride-4: pairs (j,j+4), j in {0..3,8..11}, la=(j/8)*4+j%4
#define ROTS4(CA,CB,SA,SB) do {                                                \
    ROTP(x0,x4,CA.x,SA.x);  ROTP(x1,x5,CA.y,SA.y);                             \
    ROTP(x2,x6,CA.z,SA.z);  ROTP(x3,x7,CA.w,SA.w);                             \
    ROTP(x8,x12,CB.x,SB.x); ROTP(x9,x13,CB.y,SB.y);                            \
    ROTP(x10,x14,CB.z,SB.z);ROTP(x11,x15,CB.w,SB.w); } while (0)
// stride-8: pairs (j,j+8), la=j
#define ROTS8(CA,CB,SA,SB) do {                                                \
    ROTP(x0,x8,CA.x,SA.x);  ROTP(x1,x9,CA.y,SA.y);                             \
    ROTP(x2,x10,CA.z,SA.z); ROTP(x3,x11,CA.w,SA.w);                            \
    ROTP(x4,x12,CB.x,SB.x); ROTP(x5,x13,CB.y,SB.y);                            \
    ROTP(x6,x14,CB.z,SB.z); ROTP(x7,x15,CB.w,SB.w); } while (0)

#define ACT1(X, BB) do { F2 _p = (X) + (BB);                                   \
    F2 _t = _p * _p + 1.0f;                                                    \
    F2 _r; _r.x = __builtin_amdgcn_sqrtf(_t.x);                                \
    _r.y = __builtin_amdgcn_sqrtf(_t.y);                                       \
    X = 0.5f * (_p + _r); } while (0)

// One butterfly module, M literal. NO BARRIERS: each wave owns its columns
// exclusively; intra-wave LDS RAW is satisfied by the in-order DS pipe.
#define MODULE(M) {                                                            \
  const int a0=ADDR(i0.x), a1=ADDR(i0.y), a2=ADDR(i0.z), a3=ADDR(i0.w),        \
            a4=ADDR(i1.x), a5=ADDR(i1.y), a6=ADDR(i1.z), a7=ADDR(i1.w),        \
            a8=ADDR(i2.x), a9=ADDR(i2.y), a10=ADDR(i2.z), a11=ADDR(i2.w),      \
            a12=ADDR(i3.x), a13=ADDR(i3.y), a14=ADDR(i3.z), a15=ADDR(i3.w);    \
  float4 cA,cB,sA,sB, dA,dB,tA,tB, eA,eB,uA,uB, ba,bb;                         \
  LDCS(8*(M)+0, cA,cB,sA,sB);                                                  \
  LDCS(8*(M)+1, dA,dB,tA,tB);                                                  \
  F2 x0=LD2(a0), x1=LD2(a1), x2=LD2(a2), x3=LD2(a3);                           \
  F2 x4=LD2(a4), x5=LD2(a5), x6=LD2(a6), x7=LD2(a7);                           \
  F2 x8=LD2(a8), x9=LD2(a9), x10=LD2(a10), x11=LD2(a11);                       \
  F2 x12=LD2(a12), x13=LD2(a13), x14=LD2(a14), x15=LD2(a15);                   \
  LDCS(8*(M)+2, eA,eB,uA,uB);                                                  \
  { const float4* _bp = (const float4*)(biases + (M)*N_GROW + (blk<<3));       \
    ba = _bp[0]; bb = _bp[1]; }                                                \
  ROTS1(cA,cB,sA,sB);                                                          \
  LDCS(8*(M)+3, cA,cB,sA,sB);                                                  \
  ROTS2(dA,dB,tA,tB);                                                          \
  ROTS4(eA,eB,uA,uB);                                                          \
  ROTS8(cA,cB,sA,sB);                                                          \
  ACT1(x0,ba.x); ACT1(x1,ba.y); ACT1(x2,ba.z); ACT1(x3,ba.w);                  \
  ACT1(x4,bb.x); ACT1(x5,bb.y); ACT1(x6,bb.z); ACT1(x7,bb.w);                  \
  if ((M) < 7) {                                                               \
    /* append act rows br..br+7 (same 16-row group -> +16B steps, balanced) */ \
    const int _br = N_INW + (M)*N_GROW + (blk<<3);                             \
    const int _ab = ADDR(_br);                                                 \
    ST2(_ab+  0,x0); ST2(_ab+ 16,x1); ST2(_ab+ 32,x2); ST2(_ab+ 48,x3);        \
    ST2(_ab+ 64,x4); ST2(_ab+ 80,x5); ST2(_ab+ 96,x6); ST2(_ab+112,x7);        \
    /* prefetch next module's indices */                                       \
    { const int4* _ip = (const int4*)(indices + ((M)+1)*N_INW + (blk<<4));     \
      i0=_ip[0]; i1=_ip[1]; i2=_ip[2]; i3=_ip[3]; }                            \
    LDCS(8*(M)+4, dA,dB,tA,tB);                                                \
    LDCS(8*(M)+5, eA,eB,uA,uB);                                                \
    ROTS1(dA,dB,tA,tB);                                                        \
    LDCS(8*(M)+6, dA,dB,tA,tB);                                                \
    ROTS2(eA,eB,uA,uB);                                                        \
    LDCS(8*(M)+7, eA,eB,uA,uB);                                                \
    ROTS4(dA,dB,tA,tB);                                                        \
    ROTS8(eA,eB,uA,uB);                                                        \
    ST2(a0,x0);  ST2(a1,x1);  ST2(a2,x2);  ST2(a3,x3);                         \
    ST2(a4,x4);  ST2(a5,x5);  ST2(a6,x6);  ST2(a7,x7);                         \
    ST2(a8,x8);  ST2(a9,x9);  ST2(a10,x10); ST2(a11,x11);                      \
    ST2(a12,x12); ST2(a13,x13); ST2(a14,x14); ST2(a15,x15);                    \
  } else {                                                                     \
    /* module 7: OUT rotations + scatter are dead code w.r.t. the output */    \
    *(F2*)(out + (size_t)((blk<<3)+0)*N_BATCH + cg) = x0;                      \
    *(F2*)(out + (size_t)((blk<<3)+1)*N_BATCH + cg) = x1;                      \
    *(F2*)(out + (size_t)((blk<<3)+2)*N_BATCH + cg) = x2;                      \
    *(F2*)(out + (size_t)((blk<<3)+3)*N_BATCH + cg) = x3;                      \
    *(F2*)(out + (size_t)((blk<<3)+4)*N_BATCH + cg) = x4;                      \
    *(F2*)(out + (size_t)((blk<<3)+5)*N_BATCH + cg) = x5;                      \
    *(F2*)(out + (size_t)((blk<<3)+6)*N_BATCH + cg) = x6;                      \
    *(F2*)(out + (size_t)((blk<<3)+7)*N_BATCH + cg) = x7;                      \
  } }

template <bool USE_TABLE>
__global__ __launch_bounds__(N_THREADS, 1)
void butterfly_fused_kernel(const float* __restrict__ input,
                            const float* __restrict__ scales,
                            const float* __restrict__ biases,
                            const int*   __restrict__ indices,
                            const float* __restrict__ cs_tab,
                            const float* __restrict__ angles,
                            float* __restrict__ out) {
    extern __shared__ float ldsbuf[];
    char* L = (char*)ldsbuf;
    const int t   = threadIdx.x;
    const int blk = t & 63;          // butterfly block = lane
    const int cp  = t >> 6;          // wave id = column-pair; waves fully independent
    const int cpo = cp << 3;         // byte offset of this wave's F2 slot
    // XCD swizzle: blockIdx%8 == x owns columns [x*512,(x+1)*512).
    const int b   = blockIdx.x;
    const int cg  = ((((b & 7) * 128) + (b >> 3)) << 2) + (cp << 1);

    int4 i0, i1, i2, i3;
    { const int4* ip = (const int4*)(indices + (blk << 4));
      i0 = ip[0]; i1 = ip[1]; i2 = ip[2]; i3 = ip[3]; }

    // init: rows 0..1023 = scales[r] * input[r][cg..cg+1] (this wave's 2 cols)
#pragma unroll
    for (int k = 0; k < 16; ++k) {
        const int r = (k << 6) + blk;
        F2 v = *(const F2*)(input + (size_t)r * N_BATCH + cg);
        ST2(ADDR(r), scales[r] * v);
    }

    MODULE(0) MODULE(1) MODULE(2) MODULE(3)
    MODULE(4) MODULE(5) MODULE(6) MODULE(7)
}

// ---------------- host ----------------
extern "C" void kernel_launch(void* const* d_in, const int* in_sizes, int n_in,
                              void* d_out, int out_size, void* d_ws, size_t ws_size,
                              hipStream_t stream) {
    const float* input   = (const float*)d_in[0];
    const float* scales  = (const float*)d_in[1];
    const float* angles  = (const float*)d_in[2];
    const float* biases  = (const float*)d_in[3];
    const int*   indices = (const int*)d_in[4];
    float* out = (float*)d_out;

    const size_t cs_bytes  = (size_t)N_LAYERS * 2 * 512 * sizeof(float); // 256 KB
    // 4608 rows -> 288 groups of 16 rows * 66 elems = 19008 floats = 76032 B
    const size_t lds_bytes = (size_t)288 * 66 * sizeof(float);
    const int grid = N_BATCH / 4;                                        // 1024 WGs

    if (ws_size >= cs_bytes) {
        precompute_cs_kernel<<<N_LAYERS * 512 / 256, 256, 0, stream>>>(angles, (float*)d_ws);
        butterfly_fused_kernel<true><<<grid, N_THREADS, lds_bytes, stream>>>(
            input, scales, biases, indices, (const float*)d_ws, angles, out);
    } else {
        butterfly_fused_kernel<false><<<grid, N_THREADS, lds_bytes, stream>>>(
            input, scales, biases, indices, nullptr, angles, out);
    }
}

// Round 9
// 109.177 us; speedup vs baseline: 1.2192x; 1.2192x over previous
//
#include <hip/hip_runtime.h>
#include <math.h>

#define N_INW     1024
#define N_DEPTH   8
#define N_GROW    512
#define N_BATCH   4096
#define N_THREADS 128    // 2 independent waves; wave cp owns cols {2cp,2cp+1}
#define N_LAYERS  64

typedef __attribute__((ext_vector_type(2))) float F2;
typedef decltype(__builtin_amdgcn_cvt_pkrtz(0.f, 0.f)) H2;   // half2

// cs table planes: layer g: cos plane at [(2g)*512 + p], sin plane at [(2g+1)*512 + p]
__global__ void precompute_cs_kernel(const float* __restrict__ angles,
                                     float* __restrict__ cs) {
    int i = blockIdx.x * blockDim.x + threadIdx.x;
    if (i < N_LAYERS * 512) {
        int g = i >> 9, p = i & 511;
        float a = angles[i];
        cs[(2 * g) * 512 + p]     = cosf(a);
        cs[(2 * g + 1) * 512 + p] = sinf(a);
    }
}

// fp16 LDS slab: row r, wave cp -> half2 at byte  r*8 + (r>>4)*4 + cp*4.
// 4 B pad per 16 rows: gather bank = (2*(r&15) + (r>>4)) mod 32 ~ uniform.
// Total: 288 groups * 132 B = 38016 B -> 4 WGs/CU = 8 waves/CU.
#define ADDR(r) (((r) << 3) + ((((r) >> 4)) << 2) + cpo)

#define LD2(A) ({ H2 _h = *(const H2*)(L + (A));                               \
                  F2 _v; _v.x = (float)_h.x; _v.y = (float)_h.y; _v; })
#define ST2(A, V) do { F2 _w = (V);                                            \
    *(H2*)(L + (A)) = __builtin_amdgcn_cvt_pkrtz(_w.x, _w.y); } while (0)

// load cos/sin for table layer g into four named float4s (c[0..7], s[0..7])
#define LDCS(g, CA, CB, SA, SB) do { if (USE_TABLE) {                          \
    const float4* _c = (const float4*)(cs_tab + (2*(g))*512 + (blk<<3));       \
    const float4* _s = (const float4*)(cs_tab + (2*(g)+1)*512 + (blk<<3));     \
    CA = _c[0]; CB = _c[1]; SA = _s[0]; SB = _s[1];                            \
  } else {                                                                     \
    const float4* _p = (const float4*)(angles + (g)*512 + (blk<<3));           \
    float4 _a = _p[0], _b = _p[1];                                             \
    __sincosf(_a.x, &SA.x, &CA.x); __sincosf(_a.y, &SA.y, &CA.y);              \
    __sincosf(_a.z, &SA.z, &CA.z); __sincosf(_a.w, &SA.w, &CA.w);              \
    __sincosf(_b.x, &SB.x, &CB.x); __sincosf(_b.y, &SB.y, &CB.y);              \
    __sincosf(_b.z, &SB.z, &CB.z); __sincosf(_b.w, &SB.w, &CB.w);              \
  } } while (0)

// packed 2-col rotation of one (lo,hi) pair by scalar (c,s) -> v_pk_* ops
#define ROTP(LO, HI, CC, SS) do { F2 _l = LO, _h = HI;                         \
    LO = CC * _l + SS * _h; HI = CC * _h - SS * _l; } while (0)

#define ROTS1(CA,CB,SA,SB) do {                                                \
    ROTP(x0,x1,CA.x,SA.x);  ROTP(x2,x3,CA.y,SA.y);                             \
    ROTP(x4,x5,CA.z,SA.z);  ROTP(x6,x7,CA.w,SA.w);                             \
    ROTP(x8,x9,CB.x,SB.x);  ROTP(x10,x11,CB.y,SB.y);                           \
    ROTP(x12,x13,CB.z,SB.z);ROTP(x14,x15,CB.w,SB.w); } while (0)
#define ROTS2(CA,CB,SA,SB) do {                                                \
    ROTP(x0,x2,CA.x,SA.x);  ROTP(x1,x3,CA.y,SA.y);                             \
    ROTP(x4,x6,CA.z,SA.z);  ROTP(x5,x7,CA.w,SA.w);                             \
    ROTP(x8,x10,CB.x,SB.x); ROTP(x9,x11,CB.y,SB.y);                            \
    ROTP(x12,x14,CB.z,SB.z);ROTP(x13,x15,CB.w,SB.w); } while (0)
#define ROTS4(CA,CB,SA,SB) do {                                                \
    ROTP(x0,x4,CA.x,SA.x);  ROTP(x1,x5,CA.y,SA.y);                             \
    ROTP(x2,x6,CA.z,SA.z);  ROTP(x3,x7,CA.w,SA.w);                             \
    ROTP(x8,x12,CB.x,SB.x); ROTP(x9,x13,CB.y,SB.y);                            \
    ROTP(x10,x14,CB.z,SB.z);ROTP(x11,x15,CB.w,SB.w); } while (0)
#define ROTS8(CA,CB,SA,SB) do {                                                \
    ROTP(x0,x8,CA.x,SA.x);  ROTP(x1,x9,CA.y,SA.y);                             \
    ROTP(x2,x10,CA.z,SA.z); ROTP(x3,x11,CA.w,SA.w);                            \
    ROTP(x4,x12,CB.x,SB.x); ROTP(x5,x13,CB.y,SB.y);                            \
    ROTP(x6,x14,CB.z,SB.z); ROTP(x7,x15,CB.w,SB.w); } while (0)

#define ACT1(X, BB) do { F2 _p = (X) + (BB);                                   \
    F2 _t = _p * _p + 1.0f;                                                    \
    F2 _r; _r.x = __builtin_amdgcn_sqrtf(_t.x);                                \
    _r.y = __builtin_amdgcn_sqrtf(_t.y);                                       \
    X = 0.5f * (_p + _r); } while (0)

// One butterfly module, M literal. NO BARRIERS: each wave owns its columns
// exclusively; intra-wave LDS RAW is satisfied by the in-order DS pipe.
#define MODULE(M) {                                                            \
  const int a0=ADDR(i0.x), a1=ADDR(i0.y), a2=ADDR(i0.z), a3=ADDR(i0.w),        \
            a4=ADDR(i1.x), a5=ADDR(i1.y), a6=ADDR(i1.z), a7=ADDR(i1.w),        \
            a8=ADDR(i2.x), a9=ADDR(i2.y), a10=ADDR(i2.z), a11=ADDR(i2.w),      \
            a12=ADDR(i3.x), a13=ADDR(i3.y), a14=ADDR(i3.z), a15=ADDR(i3.w);    \
  float4 cA,cB,sA,sB, dA,dB,tA,tB, eA,eB,uA,uB, ba,bb;                         \
  LDCS(8*(M)+0, cA,cB,sA,sB);                                                  \
  LDCS(8*(M)+1, dA,dB,tA,tB);                                                  \
  F2 x0=LD2(a0), x1=LD2(a1), x2=LD2(a2), x3=LD2(a3);                           \
  F2 x4=LD2(a4), x5=LD2(a5), x6=LD2(a6), x7=LD2(a7);                           \
  F2 x8=LD2(a8), x9=LD2(a9), x10=LD2(a10), x11=LD2(a11);                       \
  F2 x12=LD2(a12), x13=LD2(a13), x14=LD2(a14), x15=LD2(a15);                   \
  LDCS(8*(M)+2, eA,eB,uA,uB);                                                  \
  { const float4* _bp = (const float4*)(biases + (M)*N_GROW + (blk<<3));       \
    ba = _bp[0]; bb = _bp[1]; }                                                \
  ROTS1(cA,cB,sA,sB);                                                          \
  LDCS(8*(M)+3, cA,cB,sA,sB);                                                  \
  ROTS2(dA,dB,tA,tB);                                                          \
  ROTS4(eA,eB,uA,uB);                                                          \
  ROTS8(cA,cB,sA,sB);                                                          \
  ACT1(x0,ba.x); ACT1(x1,ba.y); ACT1(x2,ba.z); ACT1(x3,ba.w);                  \
  ACT1(x4,bb.x); ACT1(x5,bb.y); ACT1(x6,bb.z); ACT1(x7,bb.w);                  \
  if ((M) < 7) {                                                               \
    /* append act rows br..br+7 (2-way banks = free) */                        \
    const int _br = N_INW + (M)*N_GROW + (blk<<3);                             \
    const int _ab = ADDR(_br);                                                 \
    ST2(_ab+ 0,x0); ST2(_ab+ 8,x1); ST2(_ab+16,x2); ST2(_ab+24,x3);            \
    ST2(_ab+32,x4); ST2(_ab+40,x5); ST2(_ab+48,x6); ST2(_ab+56,x7);            \
    /* prefetch next module's indices */                                       \
    { const int4* _ip = (const int4*)(indices + ((M)+1)*N_INW + (blk<<4));     \
      i0=_ip[0]; i1=_ip[1]; i2=_ip[2]; i3=_ip[3]; }                            \
    LDCS(8*(M)+4, dA,dB,tA,tB);                                                \
    LDCS(8*(M)+5, eA,eB,uA,uB);                                                \
    ROTS1(dA,dB,tA,tB);                                                        \
    LDCS(8*(M)+6, dA,dB,tA,tB);                                                \
    ROTS2(eA,eB,uA,uB);                                                        \
    LDCS(8*(M)+7, eA,eB,uA,uB);                                                \
    ROTS4(dA,dB,tA,tB);                                                        \
    ROTS8(eA,eB,uA,uB);                                                        \
    ST2(a0,x0);  ST2(a1,x1);  ST2(a2,x2);  ST2(a3,x3);                         \
    ST2(a4,x4);  ST2(a5,x5);  ST2(a6,x6);  ST2(a7,x7);                         \
    ST2(a8,x8);  ST2(a9,x9);  ST2(a10,x10); ST2(a11,x11);                      \
    ST2(a12,x12); ST2(a13,x13); ST2(a14,x14); ST2(a15,x15);                    \
  } else {                                                                     \
    /* module 7: OUT rotations + scatter are dead code w.r.t. the output */    \
    *(F2*)(out + (size_t)((blk<<3)+0)*N_BATCH + cg) = x0;                      \
    *(F2*)(out + (size_t)((blk<<3)+1)*N_BATCH + cg) = x1;                      \
    *(F2*)(out + (size_t)((blk<<3)+2)*N_BATCH + cg) = x2;                      \
    *(F2*)(out + (size_t)((blk<<3)+3)*N_BATCH + cg) = x3;                      \
    *(F2*)(out + (size_t)((blk<<3)+4)*N_BATCH + cg) = x4;                      \
    *(F2*)(out + (size_t)((blk<<3)+5)*N_BATCH + cg) = x5;                      \
    *(F2*)(out + (size_t)((blk<<3)+6)*N_BATCH + cg) = x6;                      \
    *(F2*)(out + (size_t)((blk<<3)+7)*N_BATCH + cg) = x7;                      \
  } }

template <bool USE_TABLE>
__global__ __launch_bounds__(N_THREADS, 1)
void butterfly_fused_kernel(const float* __restrict__ input,
                            const float* __restrict__ scales,
                            const float* __restrict__ biases,
                            const int*   __restrict__ indices,
                            const float* __restrict__ cs_tab,
                            const float* __restrict__ angles,
                            float* __restrict__ out) {
    extern __shared__ float ldsbuf[];
    char* L = (char*)ldsbuf;
    const int t   = threadIdx.x;
    const int blk = t & 63;          // butterfly block = lane
    const int cp  = t >> 6;          // wave id = column-pair; waves fully independent
    const int cpo = cp << 2;         // byte offset of this wave's half2 slot
    // XCD swizzle: blockIdx%8 == x owns columns [x*512,(x+1)*512).
    const int b   = blockIdx.x;
    const int cg  = ((((b & 7) * 128) + (b >> 3)) << 2) + (cp << 1);

    int4 i0, i1, i2, i3;
    { const int4* ip = (const int4*)(indices + (blk << 4));
      i0 = ip[0]; i1 = ip[1]; i2 = ip[2]; i3 = ip[3]; }

    // init: rows 0..1023 = scales[r] * input[r][cg..cg+1] (this wave's 2 cols)
#pragma unroll
    for (int k = 0; k < 16; ++k) {
        const int r = (k << 6) + blk;
        F2 v = *(const F2*)(input + (size_t)r * N_BATCH + cg);
        ST2(ADDR(r), scales[r] * v);
    }

    MODULE(0) MODULE(1) MODULE(2) MODULE(3)
    MODULE(4) MODULE(5) MODULE(6) MODULE(7)
}

// ---------------- host ----------------
extern "C" void kernel_launch(void* const* d_in, const int* in_sizes, int n_in,
                              void* d_out, int out_size, void* d_ws, size_t ws_size,
                              hipStream_t stream) {
    const float* input   = (const float*)d_in[0];
    const float* scales  = (const float*)d_in[1];
    const float* angles  = (const float*)d_in[2];
    const float* biases  = (const float*)d_in[3];
    const int*   indices = (const int*)d_in[4];
    float* out = (float*)d_out;

    const size_t cs_bytes  = (size_t)N_LAYERS * 2 * 512 * sizeof(float); // 256 KB
    // 4608 rows -> 288 groups of 16 rows * 132 B = 38016 B -> 4 WGs/CU
    const size_t lds_bytes = (size_t)288 * 132;
    const int grid = N_BATCH / 4;                                        // 1024 WGs

    if (ws_size >= cs_bytes) {
        precompute_cs_kernel<<<N_LAYERS * 512 / 256, 256, 0, stream>>>(angles, (float*)d_ws);
        butterfly_fused_kernel<true><<<grid, N_THREADS, lds_bytes, stream>>>(
            input, scales, biases, indices, (const float*)d_ws, angles, out);
    } else {
        butterfly_fused_kernel<false><<<grid, N_THREADS, lds_bytes, stream>>>(
            input, scales, biases, indices, nullptr, angles, out);
    }
}

// Round 10
// 103.278 us; speedup vs baseline: 1.2888x; 1.0571x over previous
//
#include <hip/hip_runtime.h>
#include <math.h>

#define N_INW     1024
#define N_DEPTH   8
#define N_GROW    512
#define N_BATCH   4096
#define N_THREADS 128    // 2 independent waves; wave cp owns cols {2cp,2cp+1}
#define N_LAYERS  64

typedef __attribute__((ext_vector_type(2))) float F2;
typedef decltype(__builtin_amdgcn_cvt_pkrtz(0.f, 0.f)) H2;   // half2

// cs table planes: layer g: cos plane at [(2g)*512 + p], sin plane at [(2g+1)*512 + p]
__global__ void precompute_cs_kernel(const float* __restrict__ angles,
                                     float* __restrict__ cs) {
    int i = blockIdx.x * blockDim.x + threadIdx.x;
    if (i < N_LAYERS * 512) {
        int g = i >> 9, p = i & 511;
        float a = angles[i];
        cs[(2 * g) * 512 + p]     = cosf(a);
        cs[(2 * g + 1) * 512 + p] = sinf(a);
    }
}

// fp16 LDS slab: row r, wave cp -> half2 at byte  r*8 + (r>>4)*4 + cp*4.
// Total: 288 groups * 132 B = 38016 B -> 4 WGs/CU = 8 waves/CU.
#define ADDR(r) (((r) << 3) + ((((r) >> 4)) << 2) + cpo)

#define LD2(A) ({ H2 _h = *(const H2*)(L + (A));                               \
                  F2 _v; _v.x = (float)_h.x; _v.y = (float)_h.y; _v; })
#define ST2(A, V) do { F2 _w = (V);                                            \
    *(H2*)(L + (A)) = __builtin_amdgcn_cvt_pkrtz(_w.x, _w.y); } while (0)

// load cos/sin for table layer g into four named float4s (c[0..7], s[0..7])
#define LDCS(g, CA, CB, SA, SB) do { if (USE_TABLE) {                          \
    const float4* _c = (const float4*)(cs_tab + (2*(g))*512 + (blk<<3));       \
    const float4* _s = (const float4*)(cs_tab + (2*(g)+1)*512 + (blk<<3));     \
    CA = _c[0]; CB = _c[1]; SA = _s[0]; SB = _s[1];                            \
  } else {                                                                     \
    const float4* _p = (const float4*)(angles + (g)*512 + (blk<<3));           \
    float4 _a = _p[0], _b = _p[1];                                             \
    __sincosf(_a.x, &SA.x, &CA.x); __sincosf(_a.y, &SA.y, &CA.y);              \
    __sincosf(_a.z, &SA.z, &CA.z); __sincosf(_a.w, &SA.w, &CA.w);              \
    __sincosf(_b.x, &SB.x, &CB.x); __sincosf(_b.y, &SB.y, &CB.y);              \
    __sincosf(_b.z, &SB.z, &CB.z); __sincosf(_b.w, &SB.w, &CB.w);              \
  } } while (0)

// packed 2-col rotation of one (lo,hi) pair by scalar (c,s) -> v_pk_* ops
#define ROTP(LO, HI, CC, SS) do { F2 _l = LO, _h = HI;                         \
    LO = CC * _l + SS * _h; HI = CC * _h - SS * _l; } while (0)

#define ROTS1(CA,CB,SA,SB) do {                                                \
    ROTP(x0,x1,CA.x,SA.x);  ROTP(x2,x3,CA.y,SA.y);                             \
    ROTP(x4,x5,CA.z,SA.z);  ROTP(x6,x7,CA.w,SA.w);                             \
    ROTP(x8,x9,CB.x,SB.x);  ROTP(x10,x11,CB.y,SB.y);                           \
    ROTP(x12,x13,CB.z,SB.z);ROTP(x14,x15,CB.w,SB.w); } while (0)
#define ROTS2(CA,CB,SA,SB) do {                                                \
    ROTP(x0,x2,CA.x,SA.x);  ROTP(x1,x3,CA.y,SA.y);                             \
    ROTP(x4,x6,CA.z,SA.z);  ROTP(x5,x7,CA.w,SA.w);                             \
    ROTP(x8,x10,CB.x,SB.x); ROTP(x9,x11,CB.y,SB.y);                            \
    ROTP(x12,x14,CB.z,SB.z);ROTP(x13,x15,CB.w,SB.w); } while (0)
#define ROTS4(CA,CB,SA,SB) do {                                                \
    ROTP(x0,x4,CA.x,SA.x);  ROTP(x1,x5,CA.y,SA.y);                             \
    ROTP(x2,x6,CA.z,SA.z);  ROTP(x3,x7,CA.w,SA.w);                             \
    ROTP(x8,x12,CB.x,SB.x); ROTP(x9,x13,CB.y,SB.y);                            \
    ROTP(x10,x14,CB.z,SB.z);ROTP(x11,x15,CB.w,SB.w); } while (0)
#define ROTS8(CA,CB,SA,SB) do {                                                \
    ROTP(x0,x8,CA.x,SA.x);  ROTP(x1,x9,CA.y,SA.y);                             \
    ROTP(x2,x10,CA.z,SA.z); ROTP(x3,x11,CA.w,SA.w);                            \
    ROTP(x4,x12,CB.x,SB.x); ROTP(x5,x13,CB.y,SB.y);                            \
    ROTP(x6,x14,CB.z,SB.z); ROTP(x7,x15,CB.w,SB.w); } while (0)

#define ACT1(X, BB) do { F2 _p = (X) + (BB);                                   \
    F2 _t = _p * _p + 1.0f;                                                    \
    F2 _r; _r.x = __builtin_amdgcn_sqrtf(_t.x);                                \
    _r.y = __builtin_amdgcn_sqrtf(_t.y);                                       \
    X = 0.5f * (_p + _r); } while (0)

#define FENCE() __builtin_amdgcn_sched_barrier(0)

// One butterfly module, M literal. NO BARRIERS (each wave owns its columns;
// in-order DS pipe covers the intra-wave RAW). Two load blocks per module,
// each pinned with sched_barrier(0) so the backend CANNOT sink the loads to
// their consumers (which it provably did in rounds 2-9: VGPR_Count 40-56 with
// ~200 designed-live floats). IN-cs(M)/bias(M)/idx(M) were loaded in M-1.
#define MODULE(M) {                                                            \
  const int a0=ADDR(i0.x), a1=ADDR(i0.y), a2=ADDR(i0.z), a3=ADDR(i0.w),        \
            a4=ADDR(i1.x), a5=ADDR(i1.y), a6=ADDR(i1.z), a7=ADDR(i1.w),        \
            a8=ADDR(i2.x), a9=ADDR(i2.y), a10=ADDR(i2.z), a11=ADDR(i2.w),      \
            a12=ADDR(i3.x), a13=ADDR(i3.y), a14=ADDR(i3.z), a15=ADDR(i3.w);    \
  /* ---- load block A: gather + this module's OUT-phase cs ---- */            \
  F2 x0=LD2(a0), x1=LD2(a1), x2=LD2(a2), x3=LD2(a3);                           \
  F2 x4=LD2(a4), x5=LD2(a5), x6=LD2(a6), x7=LD2(a7);                           \
  F2 x8=LD2(a8), x9=LD2(a9), x10=LD2(a10), x11=LD2(a11);                       \
  F2 x12=LD2(a12), x13=LD2(a13), x14=LD2(a14), x15=LD2(a15);                   \
  float4 da0,db0,ta0,tb0, da1,db1,ta1,tb1, da2,db2,ta2,tb2, da3,db3,ta3,tb3;   \
  if ((M) < 7) {                                                               \
    LDCS(8*(M)+4, da0,db0,ta0,tb0);                                            \
    LDCS(8*(M)+5, da1,db1,ta1,tb1);                                            \
    LDCS(8*(M)+6, da2,db2,ta2,tb2);                                            \
    LDCS(8*(M)+7, da3,db3,ta3,tb3);                                            \
  }                                                                            \
  FENCE();                                                                     \
  /* ---- consume IN-cs (prefetched one module ago) ---- */                    \
  ROTS1(ca0,cb0,sa0,sb0);                                                      \
  ROTS2(ca1,cb1,sa1,sb1);                                                      \
  ROTS4(ca2,cb2,sa2,sb2);                                                      \
  ROTS8(ca3,cb3,sa3,sb3);                                                      \
  ACT1(x0,bA.x); ACT1(x1,bA.y); ACT1(x2,bA.z); ACT1(x3,bA.w);                  \
  ACT1(x4,bB.x); ACT1(x5,bB.y); ACT1(x6,bB.z); ACT1(x7,bB.w);                  \
  if ((M) < 7) {                                                               \
    /* append act rows */                                                      \
    const int _br = N_INW + (M)*N_GROW + (blk<<3);                             \
    const int _ab = ADDR(_br);                                                 \
    ST2(_ab+ 0,x0); ST2(_ab+ 8,x1); ST2(_ab+16,x2); ST2(_ab+24,x3);            \
    ST2(_ab+32,x4); ST2(_ab+40,x5); ST2(_ab+48,x6); ST2(_ab+56,x7);            \
    /* ---- load block B: next module's IN-cs + idx + bias ---- */             \
    LDCS(8*(M)+8,  ca0,cb0,sa0,sb0);                                           \
    LDCS(8*(M)+9,  ca1,cb1,sa1,sb1);                                           \
    LDCS(8*(M)+10, ca2,cb2,sa2,sb2);                                           \
    LDCS(8*(M)+11, ca3,cb3,sa3,sb3);                                           \
    { const int4* _ip = (const int4*)(indices + ((M)+1)*N_INW + (blk<<4));     \
      i0=_ip[0]; i1=_ip[1]; i2=_ip[2]; i3=_ip[3]; }                            \
    { const float4* _bp = (const float4*)(biases + ((M)+1)*N_GROW + (blk<<3)); \
      bA = _bp[0]; bB = _bp[1]; }                                              \
    FENCE();                                                                   \
    /* ---- consume OUT-cs (prefetched in block A) ---- */                     \
    ROTS1(da0,db0,ta0,tb0);                                                    \
    ROTS2(da1,db1,ta1,tb1);                                                    \
    ROTS4(da2,db2,ta2,tb2);                                                    \
    ROTS8(da3,db3,ta3,tb3);                                                    \
    ST2(a0,x0);  ST2(a1,x1);  ST2(a2,x2);  ST2(a3,x3);                         \
    ST2(a4,x4);  ST2(a5,x5);  ST2(a6,x6);  ST2(a7,x7);                         \
    ST2(a8,x8);  ST2(a9,x9);  ST2(a10,x10); ST2(a11,x11);                      \
    ST2(a12,x12); ST2(a13,x13); ST2(a14,x14); ST2(a15,x15);                    \
  } else {                                                                     \
    /* module 7: OUT rotations + scatter are dead code w.r.t. the output */    \
    *(F2*)(out + (size_t)((blk<<3)+0)*N_BATCH + cg) = x0;                      \
    *(F2*)(out + (size_t)((blk<<3)+1)*N_BATCH + cg) = x1;                      \
    *(F2*)(out + (size_t)((blk<<3)+2)*N_BATCH + cg) = x2;                      \
    *(F2*)(out + (size_t)((blk<<3)+3)*N_BATCH + cg) = x3;                      \
    *(F2*)(out + (size_t)((blk<<3)+4)*N_BATCH + cg) = x4;                      \
    *(F2*)(out + (size_t)((blk<<3)+5)*N_BATCH + cg) = x5;                      \
    *(F2*)(out + (size_t)((blk<<3)+6)*N_BATCH + cg) = x6;                      \
    *(F2*)(out + (size_t)((blk<<3)+7)*N_BATCH + cg) = x7;                      \
  } }

template <bool USE_TABLE>
__global__ __launch_bounds__(N_THREADS, 2)   // cap VGPR at 256 = the LDS-occupancy point
void butterfly_fused_kernel(const float* __restrict__ input,
                            const float* __restrict__ scales,
                            const float* __restrict__ biases,
                            const int*   __restrict__ indices,
                            const float* __restrict__ cs_tab,
                            const float* __restrict__ angles,
                            float* __restrict__ out) {
    extern __shared__ float ldsbuf[];
    char* L = (char*)ldsbuf;
    const int t   = threadIdx.x;
    const int blk = t & 63;          // butterfly block = lane
    const int cp  = t >> 6;          // wave id = column-pair; waves fully independent
    const int cpo = cp << 2;         // byte offset of this wave's half2 slot
    // XCD swizzle: blockIdx%8 == x owns columns [x*512,(x+1)*512).
    const int b   = blockIdx.x;
    const int cg  = ((((b & 7) * 128) + (b >> 3)) << 2) + (cp << 1);

    // cross-module prefetch state: IN-cs, bias, indices of the CURRENT module
    float4 ca0,cb0,sa0,sb0, ca1,cb1,sa1,sb1, ca2,cb2,sa2,sb2, ca3,cb3,sa3,sb3;
    float4 bA, bB;
    int4 i0, i1, i2, i3;

    // prologue: module 0's params
    { const int4* ip = (const int4*)(indices + (blk << 4));
      i0 = ip[0]; i1 = ip[1]; i2 = ip[2]; i3 = ip[3]; }
    LDCS(0, ca0,cb0,sa0,sb0);
    LDCS(1, ca1,cb1,sa1,sb1);
    LDCS(2, ca2,cb2,sa2,sb2);
    LDCS(3, ca3,cb3,sa3,sb3);
    { const float4* bp = (const float4*)(biases + (blk << 3));
      bA = bp[0]; bB = bp[1]; }

    // init: rows 0..1023 = scales[r] * input[r][cg..cg+1] (this wave's 2 cols)
#pragma unroll
    for (int k = 0; k < 16; ++k) {
        const int r = (k << 6) + blk;
        F2 v = *(const F2*)(input + (size_t)r * N_BATCH + cg);
        ST2(ADDR(r), scales[r] * v);
    }

    MODULE(0) MODULE(1) MODULE(2) MODULE(3)
    MODULE(4) MODULE(5) MODULE(6) MODULE(7)
}

// ---------------- host ----------------
extern "C" void kernel_launch(void* const* d_in, const int* in_sizes, int n_in,
                              void* d_out, int out_size, void* d_ws, size_t ws_size,
                              hipStream_t stream) {
    const float* input   = (const float*)d_in[0];
    const float* scales  = (const float*)d_in[1];
    const float* angles  = (const float*)d_in[2];
    const float* biases  = (const float*)d_in[3];
    const int*   indices = (const int*)d_in[4];
    float* out = (float*)d_out;

    const size_t cs_bytes  = (size_t)N_LAYERS * 2 * 512 * sizeof(float); // 256 KB
    // 4608 rows -> 288 groups of 16 rows * 132 B = 38016 B -> 4 WGs/CU
    const size_t lds_bytes = (size_t)288 * 132;
    const int grid = N_BATCH / 4;                                        // 1024 WGs

    if (ws_size >= cs_bytes) {
        precompute_cs_kernel<<<N_LAYERS * 512 / 256, 256, 0, stream>>>(angles, (float*)d_ws);
        butterfly_fused_kernel<true><<<grid, N_THREADS, lds_bytes, stream>>>(
            input, scales, biases, indices, (const float*)d_ws, angles, out);
    } else {
        butterfly_fused_kernel<false><<<grid, N_THREADS, lds_bytes, stream>>>(
            input, scales, biases, indices, nullptr, angles, out);
    }
}

// Round 11
// 102.986 us; speedup vs baseline: 1.2925x; 1.0028x over previous
//
#include <hip/hip_runtime.h>
#include <math.h>

#define N_INW     1024
#define N_DEPTH   8
#define N_GROW    512
#define N_BATCH   4096
#define N_THREADS 64     // ONE wave per WG; wave owns cols {2b', 2b'+1}
#define N_LAYERS  64

typedef __attribute__((ext_vector_type(2))) float F2;
typedef decltype(__builtin_amdgcn_cvt_pkrtz(0.f, 0.f)) H2;   // half2

// ---- setup: cs planes + precomputed LDS byte-offsets for all gathers ----
// cs layer g: cos plane [(2g)*512+p], sin plane [(2g+1)*512+p].
// addr[i] = LDS byte offset of row indices[i]:  (r + (r>>4)) << 2.
__global__ void precompute_kernel(const float* __restrict__ angles,
                                  const int*   __restrict__ indices,
                                  float* __restrict__ cs,
                                  int*   __restrict__ addrs) {
    int i = blockIdx.x * blockDim.x + threadIdx.x;
    if (i < N_LAYERS * 512) {
        int g = i >> 9, p = i & 511;
        float a = angles[i];
        cs[(2 * g) * 512 + p]     = cosf(a);
        cs[(2 * g + 1) * 512 + p] = sinf(a);
    }
    if (i < N_DEPTH * N_INW) {
        int v = indices[i];
        addrs[i] = (v + (v >> 4)) << 2;
    }
}

// fp16 slab, ONE column-pair per WG: row r -> half2 at byte (r + (r>>4))<<2.
// 4 B pad per 16 rows; total 4608*4 + 288*4 = 19584 B -> 8 WGs/CU.
#define ADDR(r) ((((r) + ((r) >> 4))) << 2)

#define LD2(A) ({ H2 _h = *(const H2*)(L + (A));                               \
                  F2 _v; _v.x = (float)_h.x; _v.y = (float)_h.y; _v; })
#define ST2(A, V) do { F2 _w = (V);                                            \
    *(H2*)(L + (A)) = __builtin_amdgcn_cvt_pkrtz(_w.x, _w.y); } while (0)

// load cos/sin for table layer g into four named float4s (c[0..7], s[0..7])
#define LDCS(g, CA, CB, SA, SB) do { if (USE_TABLE) {                          \
    const float4* _c = (const float4*)(cs_tab + (2*(g))*512 + (blk<<3));       \
    const float4* _s = (const float4*)(cs_tab + (2*(g)+1)*512 + (blk<<3));     \
    CA = _c[0]; CB = _c[1]; SA = _s[0]; SB = _s[1];                            \
  } else {                                                                     \
    const float4* _p = (const float4*)(angles + (g)*512 + (blk<<3));           \
    float4 _a = _p[0], _b = _p[1];                                             \
    __sincosf(_a.x, &SA.x, &CA.x); __sincosf(_a.y, &SA.y, &CA.y);              \
    __sincosf(_a.z, &SA.z, &CA.z); __sincosf(_a.w, &SA.w, &CA.w);              \
    __sincosf(_b.x, &SB.x, &CB.x); __sincosf(_b.y, &SB.y, &CB.y);              \
    __sincosf(_b.z, &SB.z, &CB.z); __sincosf(_b.w, &SB.w, &CB.w);              \
  } } while (0)

#define TR(v) (((v) + ((v) >> 4)) << 2)
// load the 16 gather byte-offsets for module m into i0..i3
#define LDADDR(m) do { if (USE_TABLE) {                                        \
    const int4* _ip = (const int4*)(addr_tab + (m)*N_INW + (blk<<4));          \
    i0 = _ip[0]; i1 = _ip[1]; i2 = _ip[2]; i3 = _ip[3];                        \
  } else {                                                                     \
    const int4* _ip = (const int4*)(indices + (m)*N_INW + (blk<<4));           \
    int4 _v0=_ip[0], _v1=_ip[1], _v2=_ip[2], _v3=_ip[3];                       \
    i0.x=TR(_v0.x); i0.y=TR(_v0.y); i0.z=TR(_v0.z); i0.w=TR(_v0.w);            \
    i1.x=TR(_v1.x); i1.y=TR(_v1.y); i1.z=TR(_v1.z); i1.w=TR(_v1.w);            \
    i2.x=TR(_v2.x); i2.y=TR(_v2.y); i2.z=TR(_v2.z); i2.w=TR(_v2.w);            \
    i3.x=TR(_v3.x); i3.y=TR(_v3.y); i3.z=TR(_v3.z); i3.w=TR(_v3.w);            \
  } } while (0)

// packed 2-col rotation of one (lo,hi) pair by scalar (c,s) -> v_pk_* ops
#define ROTP(LO, HI, CC, SS) do { F2 _l = LO, _h = HI;                         \
    LO = CC * _l + SS * _h; HI = CC * _h - SS * _l; } while (0)

#define ROTS1(CA,CB,SA,SB) do {                                                \
    ROTP(x0,x1,CA.x,SA.x);  ROTP(x2,x3,CA.y,SA.y);                             \
    ROTP(x4,x5,CA.z,SA.z);  ROTP(x6,x7,CA.w,SA.w);                             \
    ROTP(x8,x9,CB.x,SB.x);  ROTP(x10,x11,CB.y,SB.y);                           \
    ROTP(x12,x13,CB.z,SB.z);ROTP(x14,x15,CB.w,SB.w); } while (0)
#define ROTS2(CA,CB,SA,SB) do {                                                \
    ROTP(x0,x2,CA.x,SA.x);  ROTP(x1,x3,CA.y,SA.y);                             \
    ROTP(x4,x6,CA.z,SA.z);  ROTP(x5,x7,CA.w,SA.w);                             \
    ROTP(x8,x10,CB.x,SB.x); ROTP(x9,x11,CB.y,SB.y);                            \
    ROTP(x12,x14,CB.z,SB.z);ROTP(x13,x15,CB.w,SB.w); } while (0)
#define ROTS4(CA,CB,SA,SB) do {                                                \
    ROTP(x0,x4,CA.x,SA.x);  ROTP(x1,x5,CA.y,SA.y);                             \
    ROTP(x2,x6,CA.z,SA.z);  ROTP(x3,x7,CA.w,SA.w);                             \
    ROTP(x8,x12,CB.x,SB.x); ROTP(x9,x13,CB.y,SB.y);                            \
    ROTP(x10,x14,CB.z,SB.z);ROTP(x11,x15,CB.w,SB.w); } while (0)
#define ROTS8(CA,CB,SA,SB) do {                                                \
    ROTP(x0,x8,CA.x,SA.x);  ROTP(x1,x9,CA.y,SA.y);                             \
    ROTP(x2,x10,CA.z,SA.z); ROTP(x3,x11,CA.w,SA.w);                            \
    ROTP(x4,x12,CB.x,SB.x); ROTP(x5,x13,CB.y,SB.y);                            \
    ROTP(x6,x14,CB.z,SB.z); ROTP(x7,x15,CB.w,SB.w); } while (0)

#define ACT1(X, BB) do { F2 _p = (X) + (BB);                                   \
    F2 _t = _p * _p + 1.0f;                                                    \
    F2 _r; _r.x = __builtin_amdgcn_sqrtf(_t.x);                                \
    _r.y = __builtin_amdgcn_sqrtf(_t.y);                                       \
    X = 0.5f * (_p + _r); } while (0)

#define FENCE() __builtin_amdgcn_sched_barrier(0)

// One butterfly module, M literal. Single-wave WG: no barriers ever (in-order
// DS pipe covers intra-wave RAW). Two fenced load blocks per module keep
// prefetch distance >= half a module (proven necessary in r10: VGPR 56->112,
// dur 78.6->44.7 us when fences stopped the backend sinking the loads).
#define MODULE(M) {                                                            \
  const int a0=i0.x, a1=i0.y, a2=i0.z, a3=i0.w, a4=i1.x, a5=i1.y,              \
            a6=i1.z, a7=i1.w, a8=i2.x, a9=i2.y, a10=i2.z, a11=i2.w,            \
            a12=i3.x, a13=i3.y, a14=i3.z, a15=i3.w;                            \
  /* ---- load block A: gather + this module's OUT-phase cs ---- */            \
  F2 x0=LD2(a0), x1=LD2(a1), x2=LD2(a2), x3=LD2(a3);                           \
  F2 x4=LD2(a4), x5=LD2(a5), x6=LD2(a6), x7=LD2(a7);                           \
  F2 x8=LD2(a8), x9=LD2(a9), x10=LD2(a10), x11=LD2(a11);                       \
  F2 x12=LD2(a12), x13=LD2(a13), x14=LD2(a14), x15=LD2(a15);                   \
  float4 da0,db0,ta0,tb0, da1,db1,ta1,tb1, da2,db2,ta2,tb2, da3,db3,ta3,tb3;   \
  if ((M) < 7) {                                                               \
    LDCS(8*(M)+4, da0,db0,ta0,tb0);                                            \
    LDCS(8*(M)+5, da1,db1,ta1,tb1);                                            \
    LDCS(8*(M)+6, da2,db2,ta2,tb2);                                            \
    LDCS(8*(M)+7, da3,db3,ta3,tb3);                                            \
  }                                                                            \
  FENCE();                                                                     \
  /* ---- consume IN-cs (prefetched one module ago) ---- */                    \
  ROTS1(ca0,cb0,sa0,sb0);                                                      \
  ROTS2(ca1,cb1,sa1,sb1);                                                      \
  ROTS4(ca2,cb2,sa2,sb2);                                                      \
  ROTS8(ca3,cb3,sa3,sb3);                                                      \
  ACT1(x0,bA.x); ACT1(x1,bA.y); ACT1(x2,bA.z); ACT1(x3,bA.w);                  \
  ACT1(x4,bB.x); ACT1(x5,bB.y); ACT1(x6,bB.z); ACT1(x7,bB.w);                  \
  if ((M) < 7) {                                                               \
    /* append act rows */                                                      \
    const int _br = N_INW + (M)*N_GROW + (blk<<3);                             \
    const int _ab = ADDR(_br);                                                 \
    ST2(_ab+ 0,x0); ST2(_ab+ 4,x1); ST2(_ab+ 8,x2); ST2(_ab+12,x3);            \
    ST2(_ab+16,x4); ST2(_ab+20,x5); ST2(_ab+24,x6); ST2(_ab+28,x7);            \
    /* ---- load block B: next module's IN-cs + gather addrs + bias ---- */    \
    LDCS(8*(M)+8,  ca0,cb0,sa0,sb0);                                           \
    LDCS(8*(M)+9,  ca1,cb1,sa1,sb1);                                           \
    LDCS(8*(M)+10, ca2,cb2,sa2,sb2);                                           \
    LDCS(8*(M)+11, ca3,cb3,sa3,sb3);                                           \
    LDADDR((M)+1);                                                             \
    { const float4* _bp = (const float4*)(biases + ((M)+1)*N_GROW + (blk<<3)); \
      bA = _bp[0]; bB = _bp[1]; }                                              \
    FENCE();                                                                   \
    /* ---- consume OUT-cs (prefetched in block A) ---- */                     \
    ROTS1(da0,db0,ta0,tb0);                                                    \
    ROTS2(da1,db1,ta1,tb1);                                                    \
    ROTS4(da2,db2,ta2,tb2);                                                    \
    ROTS8(da3,db3,ta3,tb3);                                                    \
    ST2(a0,x0);  ST2(a1,x1);  ST2(a2,x2);  ST2(a3,x3);                         \
    ST2(a4,x4);  ST2(a5,x5);  ST2(a6,x6);  ST2(a7,x7);                         \
    ST2(a8,x8);  ST2(a9,x9);  ST2(a10,x10); ST2(a11,x11);                      \
    ST2(a12,x12); ST2(a13,x13); ST2(a14,x14); ST2(a15,x15);                    \
  } else {                                                                     \
    /* module 7: OUT rotations + scatter are dead code w.r.t. the output */    \
    *(F2*)(out + (size_t)((blk<<3)+0)*N_BATCH + cg) = x0;                      \
    *(F2*)(out + (size_t)((blk<<3)+1)*N_BATCH + cg) = x1;                      \
    *(F2*)(out + (size_t)((blk<<3)+2)*N_BATCH + cg) = x2;                      \
    *(F2*)(out + (size_t)((blk<<3)+3)*N_BATCH + cg) = x3;                      \
    *(F2*)(out + (size_t)((blk<<3)+4)*N_BATCH + cg) = x4;                      \
    *(F2*)(out + (size_t)((blk<<3)+5)*N_BATCH + cg) = x5;                      \
    *(F2*)(out + (size_t)((blk<<3)+6)*N_BATCH + cg) = x6;                      \
    *(F2*)(out + (size_t)((blk<<3)+7)*N_BATCH + cg) = x7;                      \
  } }

template <bool USE_TABLE>
__global__ __launch_bounds__(N_THREADS, 2)   // 2 waves/EU = 8 WGs/CU (the LDS cap)
void butterfly_fused_kernel(const float* __restrict__ input,
                            const float* __restrict__ scales,
                            const float* __restrict__ biases,
                            const int*   __restrict__ indices,
                            const float* __restrict__ cs_tab,
                            const int*   __restrict__ addr_tab,
                            const float* __restrict__ angles,
                            float* __restrict__ out) {
    extern __shared__ float ldsbuf[];
    char* L = (char*)ldsbuf;
    const int blk = threadIdx.x;     // butterfly block = lane (single-wave WG)
    // XCD swizzle: blockIdx%8 == x owns columns [x*512,(x+1)*512).
    const int b   = blockIdx.x;
    const int cg  = (((b & 7) * 256) + (b >> 3)) * 2;

    // cross-module prefetch state: IN-cs, bias, gather addrs of CURRENT module
    float4 ca0,cb0,sa0,sb0, ca1,cb1,sa1,sb1, ca2,cb2,sa2,sb2, ca3,cb3,sa3,sb3;
    float4 bA, bB;
    int4 i0, i1, i2, i3;

    // prologue: module 0's params
    LDADDR(0);
    LDCS(0, ca0,cb0,sa0,sb0);
    LDCS(1, ca1,cb1,sa1,sb1);
    LDCS(2, ca2,cb2,sa2,sb2);
    LDCS(3, ca3,cb3,sa3,sb3);
    { const float4* bp = (const float4*)(biases + (blk << 3));
      bA = bp[0]; bB = bp[1]; }

    // init: rows 0..1023 = scales[r] * input[r][cg..cg+1]
#pragma unroll
    for (int k = 0; k < 16; ++k) {
        const int r = (k << 6) + blk;
        F2 v = *(const F2*)(input + (size_t)r * N_BATCH + cg);
        ST2(ADDR(r), scales[r] * v);
    }

    MODULE(0) MODULE(1) MODULE(2) MODULE(3)
    MODULE(4) MODULE(5) MODULE(6) MODULE(7)
}

// ---------------- host ----------------
extern "C" void kernel_launch(void* const* d_in, const int* in_sizes, int n_in,
                              void* d_out, int out_size, void* d_ws, size_t ws_size,
                              hipStream_t stream) {
    const float* input   = (const float*)d_in[0];
    const float* scales  = (const float*)d_in[1];
    const float* angles  = (const float*)d_in[2];
    const float* biases  = (const float*)d_in[3];
    const int*   indices = (const int*)d_in[4];
    float* out = (float*)d_out;

    const size_t cs_bytes  = (size_t)N_LAYERS * 2 * 512 * sizeof(float);   // 256 KB
    const size_t adr_bytes = (size_t)N_DEPTH * N_INW * sizeof(int);        // 32 KB
    // fp16 slab: 4608*4 + 288*4 = 19584 B per WG -> 8 WGs/CU
    const size_t lds_bytes = (size_t)4608 * 4 + 288 * 4;
    const int grid = N_BATCH / 2;                                          // 2048 WGs

    if (ws_size >= cs_bytes + adr_bytes) {
        float* cs  = (float*)d_ws;
        int* addrs = (int*)((char*)d_ws + cs_bytes);
        precompute_kernel<<<N_LAYERS * 512 / 256, 256, 0, stream>>>(angles, indices, cs, addrs);
        butterfly_fused_kernel<true><<<grid, N_THREADS, lds_bytes, stream>>>(
            input, scales, biases, indices, cs, addrs, angles, out);
    } else {
        butterfly_fused_kernel<false><<<grid, N_THREADS, lds_bytes, stream>>>(
            input, scales, biases, indices, nullptr, nullptr, angles, out);
    }
}